// Round 5
// baseline (1703.614 us; speedup 1.0000x reference)
//
#include <hip/hip_runtime.h>
#include <hip/hip_bf16.h>

#define NFLOW 20000
#define NMEMB 5000
#define EFFN  100000
#define EMFN  80000

using short8 = __attribute__((ext_vector_type(8))) short;
using f32x16 = __attribute__((ext_vector_type(16))) float;

__device__ __forceinline__ short bf16s(float f) {
  __hip_bfloat16 h = __float2bfloat16(f);
  return *reinterpret_cast<short*>(&h);
}

__device__ __forceinline__ void gl_lds16(const void* g, void* l) {
  __builtin_amdgcn_global_load_lds(
      (const __attribute__((address_space(1))) unsigned int*)g,
      (__attribute__((address_space(3))) unsigned int*)l, 16, 0, 0);
}

__device__ __forceinline__ void atomicMaxFloat(float* addr, float val) {
  int* ai = (int*)addr;
  int old = __float_as_int(*addr);
  while (__int_as_float(old) < val) {
    int assumed = old;
    old = atomicCAS(ai, assumed, __float_as_int(val));
    if (old == assumed) break;
  }
}

// ---------------- init ----------------
__global__ __launch_bounds__(256) void k_init(float* __restrict__ xc,
                                              float* __restrict__ aggr,
                                              float* __restrict__ m,
                                              float* __restrict__ z,
                                              float* __restrict__ xsum) {
  int i = blockIdx.x * 256 + threadIdx.x;
  if (i < NFLOW * 64) { xc[i] = 0.f; aggr[i] = 0.f; xsum[i] = 0.f; }
  if (i < NFLOW) { m[i] = __int_as_float(0xff800000); z[i] = 0.f; }
}

// ------------- transpose+cvt: out[c*R+r] = bf16(in[r*C+c]) -------------
__global__ __launch_bounds__(256) void k_transpose(const float* __restrict__ in,
                                                   unsigned short* __restrict__ out,
                                                   int R, int C) {
  __shared__ unsigned short tile[64][66];
  const int t = threadIdx.x;
  const int r0 = blockIdx.x * 64, c0 = blockIdx.y * 64;
  {
    int r = t >> 2;
    int cb = (t & 3) * 16;
#pragma unroll
    for (int q = 0; q < 4; ++q) {
      float4 v = *(const float4*)(in + (size_t)(r0 + r) * C + c0 + cb + q * 4);
      tile[r][cb + q * 4 + 0] = (unsigned short)bf16s(v.x);
      tile[r][cb + q * 4 + 1] = (unsigned short)bf16s(v.y);
      tile[r][cb + q * 4 + 2] = (unsigned short)bf16s(v.z);
      tile[r][cb + q * 4 + 3] = (unsigned short)bf16s(v.w);
    }
  }
  __syncthreads();
  {
    int c = t >> 2;
    int rb = (t & 3) * 16;
#pragma unroll
    for (int q = 0; q < 4; ++q) {
      int r = rb + q * 4;
      ushort4 v = make_ushort4(tile[r][c], tile[r + 1][c], tile[r + 2][c], tile[r + 3][c]);
      *(ushort4*)(out + (size_t)(c0 + c) * R + r0 + r) = v;
    }
  }
}

// ---------------- Y(N,64) = X(N,64) @ W(64,64) ----------------
__global__ __launch_bounds__(256) void k_linear64(const float* __restrict__ X,
                                                  const float* __restrict__ W,
                                                  float* __restrict__ Y, int N) {
  __shared__ float Ws[64 * 64];
  __shared__ float Xs[4][65];
  const int t = threadIdx.x;
  for (int i = t; i < 4096; i += 256) Ws[i] = W[i];
  const int r = t >> 6, f = t & 63;
  const int n = blockIdx.x * 4 + r;
  Xs[r][f] = (n < N) ? X[n * 64 + f] : 0.f;
  __syncthreads();
  if (n < N) {
    float s = 0.f;
#pragma unroll
    for (int d = 0; d < 64; ++d) s += Xs[r][d] * Ws[d * 64 + f];
    Y[n * 64 + f] = s;
  }
}

// ---------------- attention scores + segment max ----------------
__global__ __launch_bounds__(256) void k_score(const float* __restrict__ q,
                                               const float* __restrict__ kb,
                                               const float* __restrict__ ea_mf,
                                               const int* __restrict__ ei_mf,
                                               const float* __restrict__ We,
                                               float* __restrict__ score,
                                               float* __restrict__ m) {
  const int t = threadIdx.x;
  const int e = blockIdx.x * 4 + (t >> 6);
  const int lane = t & 63;
  if (e >= EMFN) return;
  const int sm = ei_mf[e];
  const int df = ei_mf[EMFN + e];
  float ke = kb[sm * 64 + lane];
#pragma unroll
  for (int i = 0; i < 6; ++i) ke += ea_mf[e * 6 + i] * We[i * 64 + lane];
  float s = q[df * 64 + lane] * ke;
#pragma unroll
  for (int o = 32; o; o >>= 1) s += __shfl_xor(s, o, 64);
  s *= 0.125f;
  if (lane == 0) {
    score[e] = s;
    atomicMaxFloat(&m[df], s);
  }
}

// ---------------- a=exp(score-m); z += a; xc += a*v[src] ----------------
__global__ __launch_bounds__(256) void k_az(const float* __restrict__ score,
                                            const float* __restrict__ m,
                                            const int* __restrict__ ei_mf,
                                            const float* __restrict__ vb,
                                            float* __restrict__ z,
                                            float* __restrict__ xc) {
  const int t = threadIdx.x;
  const int e = blockIdx.x * 4 + (t >> 6);
  const int lane = t & 63;
  if (e >= EMFN) return;
  const int sm = ei_mf[e];
  const int df = ei_mf[EMFN + e];
  const float a = expf(score[e] - m[df]);
  if (lane == 0) atomicAdd(&z[df], a);
  atomicAdd(&xc[df * 64 + lane], a * vb[sm * 64 + lane]);
}

// ============ fused edge MLP + contraction (MFMA), 512 threads ============
// R1 (69,632 B): {w0s|bk0s|eas} -> BtC[512][128] -> h1sT[512][136B] -> pbuf[64][66]f32
// R2 (65,536 B): h0s swz bf16 (64KB) -> { xs[64][72]bf16 (9216) | wave rings 8x3x2KB }
// Wave-private B staging: wave (p,jj) needs kappa = (2kb+p)*64 + 16*jj + 0..15 for all
// f=0..63  ->  2KB slice, disjoint across waves  ->  NO barrier in the 256-iter loop.
__device__ __forceinline__ void stage_k2w(const unsigned short* Wk2T, char* slotp,
                                          int kb, int p, int jj, int lane) {
  size_t kap0 = (size_t)(2 * kb + p) * 64 + 16 * jj;
  const char* g = (const char*)Wk2T + (size_t)lane * 65536 + kap0 * 2;
  gl_lds16(g, slotp);            // LDS[f=lane][kappa 0..7 of slice]
  gl_lds16(g + 16, slotp + 1024);  // LDS[f=lane][kappa 8..15 of slice]
}

__global__ __launch_bounds__(512, 1) void k_edge(
    const float* __restrict__ x_flow, const float* __restrict__ ea_ff,
    const int* __restrict__ ei_ff,
    const float* __restrict__ Wk0, const float* __restrict__ bk0,
    const float* __restrict__ bk1,
    const unsigned short* __restrict__ Wk1T,   // [512 n][512 k] bf16
    const unsigned short* __restrict__ Wk2T,   // [64 f][32768 kappa] bf16
    float* __restrict__ aggr, float* __restrict__ xsum) {
  __shared__ __align__(16) char LDS[135168];
  char* R1 = LDS;
  char* R2 = LDS + 69632;
  const int t = threadIdx.x;
  const int w = t >> 6, lane = t & 63, half = lane >> 5;
  const int e0g = blockIdx.x * 64;

  // ---- stage Wk0, bk0, ea tile ----
  float* w0s  = (float*)R1;            // [6][512]
  float* bk0s = (float*)(R1 + 12288);  // [512]
  float* eas  = (float*)(R1 + 14336);  // [64][6]
  for (int i = t; i < 3072; i += 512) w0s[i] = Wk0[i];
  if (t < 512) bk0s[t] = bk0[t];
  if (t < 384) {
    int g = e0g * 6 + t;
    eas[t] = (g < EFFN * 6) ? ea_ff[g] : 0.f;
  }
  __syncthreads();

  // ---- h0 = relu(ea@Wk0+bk0) -> R2 swizzled bf16 ----
  {
    int e = t >> 3, c0 = (t & 7) * 64;
    float ea[6];
#pragma unroll
    for (int i = 0; i < 6; ++i) ea[i] = eas[e * 6 + i];
#pragma unroll
    for (int s8 = 0; s8 < 8; ++s8) {
      int kbase = c0 + s8 * 8;
      float s[8];
      float4 b0 = *(const float4*)(bk0s + kbase);
      float4 b1 = *(const float4*)(bk0s + kbase + 4);
      s[0]=b0.x; s[1]=b0.y; s[2]=b0.z; s[3]=b0.w; s[4]=b1.x; s[5]=b1.y; s[6]=b1.z; s[7]=b1.w;
#pragma unroll
      for (int i = 0; i < 6; ++i) {
        float4 w0 = *(const float4*)(w0s + i * 512 + kbase);
        float4 w1 = *(const float4*)(w0s + i * 512 + kbase + 4);
        s[0] = fmaf(ea[i], w0.x, s[0]); s[1] = fmaf(ea[i], w0.y, s[1]);
        s[2] = fmaf(ea[i], w0.z, s[2]); s[3] = fmaf(ea[i], w0.w, s[3]);
        s[4] = fmaf(ea[i], w1.x, s[4]); s[5] = fmaf(ea[i], w1.y, s[5]);
        s[6] = fmaf(ea[i], w1.z, s[6]); s[7] = fmaf(ea[i], w1.w, s[7]);
      }
      short8 v;
#pragma unroll
      for (int j = 0; j < 8; ++j) v[j] = bf16s(fmaxf(s[j], 0.f));
      int slot = (kbase >> 3) ^ (e & 15);
      *(short8*)(R2 + e * 1024 + slot * 16) = v;
    }
  }
  __syncthreads();

  // ---- h1 = relu(h0 @ Wk1 + bk1) -> h1sT[n][e] bf16, single 512-n pass ----
  char* BtC = R1;  // [512 n][128 B] (w0s/bk0s/eas dead)
  {
    f32x16 acc[2][2];
#pragma unroll
    for (int m = 0; m < 2; ++m)
#pragma unroll
      for (int n = 0; n < 2; ++n)
#pragma unroll
        for (int r = 0; r < 16; ++r) acc[m][n][r] = 0.f;
    for (int kc = 0; kc < 8; ++kc) {
#pragma unroll
      for (int i = 0; i < 8; ++i) {
        int row = w * 64 + i * 8 + (lane >> 3);
        int slot = (lane & 7) ^ (row & 7);
        const char* g = (const char*)Wk1T + (size_t)row * 1024 + kc * 128 + slot * 16;
        gl_lds16(g, BtC + (w * 64 + i * 8) * 128);
      }
      __syncthreads();
#pragma unroll
      for (int ks = 0; ks < 4; ++ks) {
        short8 a[2], b[2];
#pragma unroll
        for (int m = 0; m < 2; ++m) {
          int e = (lane & 31) + 32 * m;
          int slot = ((kc * 64 + ks * 16 + half * 8) >> 3) ^ (e & 15);
          a[m] = *(const short8*)(R2 + e * 1024 + slot * 16);
        }
#pragma unroll
        for (int n = 0; n < 2; ++n) {
          int nl = w * 64 + n * 32 + (lane & 31);
          int slot = (2 * ks + half) ^ (nl & 7);
          b[n] = *(const short8*)(BtC + nl * 128 + slot * 16);
        }
#pragma unroll
        for (int m = 0; m < 2; ++m)
#pragma unroll
          for (int n = 0; n < 2; ++n)
            acc[m][n] = __builtin_amdgcn_mfma_f32_32x32x16_bf16(a[m], b[n], acc[m][n], 0, 0, 0);
      }
      __syncthreads();
    }
    // epilogue: h1sT[n][e] (transposed, stride 136 B), overwrites BtC
#pragma unroll
    for (int n = 0; n < 2; ++n) {
      int nl = w * 64 + n * 32 + (lane & 31);
      float b1 = bk1[nl];
#pragma unroll
      for (int m = 0; m < 2; ++m) {
#pragma unroll
        for (int rq = 0; rq < 4; ++rq) {
          int e0 = 32 * m + 8 * rq + 4 * half;
          unsigned short u0 = (unsigned short)bf16s(fmaxf(acc[m][n][rq * 4 + 0] + b1, 0.f));
          unsigned short u1 = (unsigned short)bf16s(fmaxf(acc[m][n][rq * 4 + 1] + b1, 0.f));
          unsigned short u2 = (unsigned short)bf16s(fmaxf(acc[m][n][rq * 4 + 2] + b1, 0.f));
          unsigned short u3 = (unsigned short)bf16s(fmaxf(acc[m][n][rq * 4 + 3] + b1, 0.f));
          uint2 val = make_uint2((unsigned)u0 | ((unsigned)u1 << 16),
                                 (unsigned)u2 | ((unsigned)u3 << 16));
          *(uint2*)(R1 + nl * 136 + e0 * 2) = val;
        }
      }
    }
    __syncthreads();
  }

  // ---- stage xs (bf16 [64][72]) + xsum atomics ----
  unsigned short* xs = (unsigned short*)R2;
  {
    int row = t >> 3, c0 = (t & 7) * 8;
    int eg = e0g + row;
    bool valid = eg < EFFN;
    int src = valid ? ei_ff[eg] : 0;
    int dst = valid ? ei_ff[EFFN + eg] : 0;
    float4 v0 = valid ? *(const float4*)(x_flow + (size_t)src * 64 + c0)
                      : make_float4(0.f, 0.f, 0.f, 0.f);
    float4 v1 = valid ? *(const float4*)(x_flow + (size_t)src * 64 + c0 + 4)
                      : make_float4(0.f, 0.f, 0.f, 0.f);
    short8 u;
    u[0] = bf16s(v0.x); u[1] = bf16s(v0.y); u[2] = bf16s(v0.z); u[3] = bf16s(v0.w);
    u[4] = bf16s(v1.x); u[5] = bf16s(v1.y); u[6] = bf16s(v1.z); u[7] = bf16s(v1.w);
    *(short8*)(xs + row * 72 + c0) = u;
    if (valid) {
      atomicAdd(&xsum[dst * 64 + c0 + 0], v0.x);
      atomicAdd(&xsum[dst * 64 + c0 + 1], v0.y);
      atomicAdd(&xsum[dst * 64 + c0 + 2], v0.z);
      atomicAdd(&xsum[dst * 64 + c0 + 3], v0.w);
      atomicAdd(&xsum[dst * 64 + c0 + 4], v1.x);
      atomicAdd(&xsum[dst * 64 + c0 + 5], v1.y);
      atomicAdd(&xsum[dst * 64 + c0 + 6], v1.z);
      atomicAdd(&xsum[dst * 64 + c0 + 7], v1.w);
    }
  }
  __syncthreads();  // drains vmcnt (compiler emits vmcnt(0) before barrier)

  // ---- per-wave slice: p = kw parity, jj = 16-d slice ----
  const int p = w >> 2, jj = w & 3;
  const int d0 = 16 * jj + 8 * half;

  // ---- wave-private ring: 3 slots x 2KB per wave, NO barriers in loop ----
  char* myring = R2 + 9216 + w * 6144;
  stage_k2w(Wk2T, myring, 0, p, jj, lane);
  stage_k2w(Wk2T, myring + 2048, 1, p, jj, lane);

  float xr[2][8];
#pragma unroll
  for (int m = 0; m < 2; ++m) {
    int row = (lane & 31) + 32 * m;
    short8 xv = *(const short8*)(xs + row * 72 + d0);
#pragma unroll
    for (int j = 0; j < 8; ++j)
      xr[m][j] = __uint_as_float(((unsigned)(unsigned short)xv[j]) << 16);
  }

  f32x16 acc[2][2];
#pragma unroll
  for (int m = 0; m < 2; ++m)
#pragma unroll
    for (int n = 0; n < 2; ++n)
#pragma unroll
      for (int r = 0; r < 16; ++r) acc[m][n][r] = 0.f;

  for (int kb = 0; kb < 256; ++kb) {
    if (kb < 255) {
      asm volatile("s_waitcnt vmcnt(2)" ::: "memory");
    } else {
      asm volatile("s_waitcnt vmcnt(0)" ::: "memory");
    }
    if (kb < 254) {
      int s = (kb + 2) % 3;
      stage_k2w(Wk2T, myring + s * 2048, kb + 2, p, jj, lane);
    }
    char* cur = myring + (kb % 3) * 2048;
    const int kw = 2 * kb + p;
    float hm[2];
#pragma unroll
    for (int m = 0; m < 2; ++m) {
      unsigned short hb = *(const unsigned short*)(R1 + kw * 136 + ((lane & 31) + 32 * m) * 2);
      hm[m] = __uint_as_float((unsigned int)hb << 16);
    }
    short8 b[2];
#pragma unroll
    for (int n = 0; n < 2; ++n) {
      int f = n * 32 + (lane & 31);
      b[n] = *(const short8*)(cur + half * 1024 + f * 16);
    }
    short8 a[2];
#pragma unroll
    for (int m = 0; m < 2; ++m)
#pragma unroll
      for (int j = 0; j < 8; ++j) a[m][j] = bf16s(hm[m] * xr[m][j]);
    __builtin_amdgcn_s_setprio(1);
#pragma unroll
    for (int m = 0; m < 2; ++m)
#pragma unroll
      for (int n = 0; n < 2; ++n)
        acc[m][n] = __builtin_amdgcn_mfma_f32_32x32x16_bf16(a[m], b[n], acc[m][n], 0, 0, 0);
    __builtin_amdgcn_s_setprio(0);
  }
  __syncthreads();  // all waves done with h1sT; reuse R1 for pbuf

  // ---- cross-wave reduce via LDS atomics + segment-sum global atomics ----
  float* pbuf = (float*)R1;  // [64][66]
  for (int i = t; i < 4224; i += 512) pbuf[i] = 0.f;
  __syncthreads();
#pragma unroll
  for (int m = 0; m < 2; ++m)
#pragma unroll
    for (int n = 0; n < 2; ++n)
#pragma unroll
      for (int r = 0; r < 16; ++r) {
        int e = 32 * m + (r & 3) + 8 * (r >> 2) + 4 * half;
        int f = 32 * n + (lane & 31);
        atomicAdd(&pbuf[e * 66 + f], acc[m][n][r]);
      }
  __syncthreads();
  for (int idx = t; idx < 4096; idx += 512) {
    int e = idx >> 6, f = idx & 63;
    int eg = e0g + e;
    if (eg < EFFN) atomicAdd(&aggr[ei_ff[EFFN + eg] * 64 + f], pbuf[e * 66 + f]);
  }
}

// ---------------- final: Wroot/Wo/bk2 applies, FiLM, silu ----------------
__global__ __launch_bounds__(256) void k_final(
    const float* __restrict__ x_flow, const float* __restrict__ aggr,
    const float* __restrict__ xc, const float* __restrict__ z,
    const float* __restrict__ xsum, const float* __restrict__ bk2,
    const float* __restrict__ Wroot, const float* __restrict__ broot,
    const float* __restrict__ Wo, const float* __restrict__ bo,
    const float* __restrict__ tau, const float* __restrict__ Wt1,
    const float* __restrict__ bt1, const float* __restrict__ Wt2,
    const float* __restrict__ bt2, float* __restrict__ out) {
  __shared__ float WoS[4096], WrS[4096], B2S[4096], ssS[128], tembS[64];
  __shared__ float xcnS[4][65], xfS[4][65], xsS[4][65];
  const int t = threadIdx.x;
  for (int i = t; i < 4096; i += 256) { WoS[i] = Wo[i]; WrS[i] = Wroot[i]; B2S[i] = bk2[i]; }
  if (t < 64) {
    float y = tau[0] * Wt1[t] + bt1[t];
    tembS[t] = y / (1.f + expf(-y));
  }
  __syncthreads();
  if (t < 128) {
    float s = bt2[t];
#pragma unroll
    for (int d = 0; d < 64; ++d) s += tembS[d] * Wt2[d * 128 + t];
    ssS[t] = s;
  }
  const int r = t >> 6, f = t & 63;
  const int n = blockIdx.x * 4 + r;
  if (n < NFLOW) {
    float zr = z[n];
    xcnS[r][f] = xc[n * 64 + f] / (zr + 1e-9f);
    xfS[r][f] = x_flow[n * 64 + f];
    xsS[r][f] = xsum[n * 64 + f];
  }
  __syncthreads();
  if (n < NFLOW) {
    float cross = bo[f], root = broot[f], rb = 0.f;
#pragma unroll
    for (int d = 0; d < 64; ++d) {
      cross += xcnS[r][d] * WoS[d * 64 + f];
      root += xfS[r][d] * WrS[d * 64 + f];
      rb += xsS[r][d] * B2S[d * 64 + f];
    }
    float g = root + rb + aggr[n * 64 + f] + cross;
    g = fmaxf(g, 0.f);
    float y = g * (1.f + ssS[f]) + ssS[64 + f];
    out[n * 64 + f] = y / (1.f + expf(-y));
  }
}

extern "C" void kernel_launch(void* const* d_in, const int* in_sizes, int n_in,
                              void* d_out, int out_size, void* d_ws, size_t ws_size,
                              hipStream_t stream) {
  const float* x_flow = (const float*)d_in[0];
  const float* x_memb = (const float*)d_in[1];
  const float* ea_ff  = (const float*)d_in[2];
  const float* ea_mf  = (const float*)d_in[3];
  const float* tau    = (const float*)d_in[4];
  const int*   ei_ff  = (const int*)d_in[5];
  const int*   ei_mf  = (const int*)d_in[6];
  const float* Wk0 = (const float*)d_in[7],  *bk0 = (const float*)d_in[8];
  const float* Wk1 = (const float*)d_in[9],  *bk1 = (const float*)d_in[10];
  const float* Wk2 = (const float*)d_in[11], *bk2 = (const float*)d_in[12];
  const float* Wroot = (const float*)d_in[13], *broot = (const float*)d_in[14];
  const float* Wq = (const float*)d_in[15];
  const float* Wkk = (const float*)d_in[16];
  const float* Wv = (const float*)d_in[17];
  const float* We = (const float*)d_in[18];
  const float* Wo = (const float*)d_in[19], *bo = (const float*)d_in[20];
  const float* Wt1 = (const float*)d_in[21], *bt1 = (const float*)d_in[22];
  const float* Wt2 = (const float*)d_in[23], *bt2 = (const float*)d_in[24];

  float* ws = (float*)d_ws;
  float* xc    = ws;                    // NF*64
  float* aggr  = xc + NFLOW * 64;       // NF*64
  float* m     = aggr + NFLOW * 64;     // NF
  float* z     = m + NFLOW;             // NF
  float* score = z + NFLOW;             // EMF
  float* q     = score + EMFN;          // NF*64
  float* kb    = q + NFLOW * 64;        // NM*64
  float* vb    = kb + NMEMB * 64;       // NM*64
  float* xsum  = vb + NMEMB * 64;       // NF*64
  unsigned short* Wk1T = (unsigned short*)(xsum + NFLOW * 64);  // 512*512 bf16
  unsigned short* Wk2T = Wk1T + 512 * 512;                      // 64*32768 bf16
  float* out = (float*)d_out;

  k_init<<<(NFLOW * 64 + 255) / 256, 256, 0, stream>>>(xc, aggr, m, z, xsum);
  {
    dim3 g1(8, 8);
    k_transpose<<<g1, 256, 0, stream>>>(Wk1, Wk1T, 512, 512);
    dim3 g2(512, 1);
    k_transpose<<<g2, 256, 0, stream>>>(Wk2, Wk2T, 32768, 64);
  }
  k_linear64<<<(NFLOW + 3) / 4, 256, 0, stream>>>(x_flow, Wq, q, NFLOW);
  k_linear64<<<(NMEMB + 3) / 4, 256, 0, stream>>>(x_memb, Wkk, kb, NMEMB);
  k_linear64<<<(NMEMB + 3) / 4, 256, 0, stream>>>(x_memb, Wv, vb, NMEMB);
  k_score<<<EMFN / 4, 256, 0, stream>>>(q, kb, ea_mf, ei_mf, We, score, m);
  k_az<<<EMFN / 4, 256, 0, stream>>>(score, m, ei_mf, vb, z, xc);
  k_edge<<<(EFFN + 63) / 64, 512, 0, stream>>>(x_flow, ea_ff, ei_ff,
                                               Wk0, bk0, bk1, Wk1T, Wk2T, aggr, xsum);
  k_final<<<(NFLOW + 3) / 4, 256, 0, stream>>>(x_flow, aggr, xc, z, xsum, bk2,
                                               Wroot, broot, Wo, bo, tau, Wt1, bt1,
                                               Wt2, bt2, out);
}

// Round 6
// 1427.306 us; speedup vs baseline: 1.1936x; 1.1936x over previous
//
#include <hip/hip_runtime.h>
#include <hip/hip_bf16.h>

#define NFLOW 20000
#define NMEMB 5000
#define EFFN  100000
#define EMFN  80000
#define PAD_E 100352  // 392 tiles of 256 / 1568 tiles of 64

using short8 = __attribute__((ext_vector_type(8))) short;
using f32x16 = __attribute__((ext_vector_type(16))) float;

__device__ __forceinline__ short bf16s(float f) {
  __hip_bfloat16 h = __float2bfloat16(f);
  return *reinterpret_cast<short*>(&h);
}

__device__ __forceinline__ void gl_lds16(const void* g, void* l) {
  __builtin_amdgcn_global_load_lds(
      (const __attribute__((address_space(1))) unsigned int*)g,
      (__attribute__((address_space(3))) unsigned int*)l, 16, 0, 0);
}

__device__ __forceinline__ void atomicMaxFloat(float* addr, float val) {
  int* ai = (int*)addr;
  int old = __float_as_int(*addr);
  while (__int_as_float(old) < val) {
    int assumed = old;
    old = atomicCAS(ai, assumed, __float_as_int(val));
    if (old == assumed) break;
  }
}

// ---------------- init ----------------
__global__ __launch_bounds__(256) void k_init(float* __restrict__ xc,
                                              float* __restrict__ aggr,
                                              float* __restrict__ m,
                                              float* __restrict__ z,
                                              float* __restrict__ xsum) {
  int i = blockIdx.x * 256 + threadIdx.x;
  if (i < NFLOW * 64) { xc[i] = 0.f; aggr[i] = 0.f; xsum[i] = 0.f; }
  if (i < NFLOW) { m[i] = __int_as_float(0xff800000); z[i] = 0.f; }
}

// ------------- transpose+cvt: out[c*R+r] = bf16(in[r*C+c]) (for Wk1T) -------
__global__ __launch_bounds__(256) void k_transpose(const float* __restrict__ in,
                                                   unsigned short* __restrict__ out,
                                                   int R, int C) {
  __shared__ unsigned short tile[64][66];
  const int t = threadIdx.x;
  const int r0 = blockIdx.x * 64, c0 = blockIdx.y * 64;
  {
    int r = t >> 2;
    int cb = (t & 3) * 16;
#pragma unroll
    for (int q = 0; q < 4; ++q) {
      float4 v = *(const float4*)(in + (size_t)(r0 + r) * C + c0 + cb + q * 4);
      tile[r][cb + q * 4 + 0] = (unsigned short)bf16s(v.x);
      tile[r][cb + q * 4 + 1] = (unsigned short)bf16s(v.y);
      tile[r][cb + q * 4 + 2] = (unsigned short)bf16s(v.z);
      tile[r][cb + q * 4 + 3] = (unsigned short)bf16s(v.w);
    }
  }
  __syncthreads();
  {
    int c = t >> 2;
    int rb = (t & 3) * 16;
#pragma unroll
    for (int q = 0; q < 4; ++q) {
      int r = rb + q * 4;
      ushort4 v = make_ushort4(tile[r][c], tile[r + 1][c], tile[r + 2][c], tile[r + 3][c]);
      *(ushort4*)(out + (size_t)(c0 + c) * R + r0 + r) = v;
    }
  }
}

// ---- k_prep2: Wk2F[kb][f][pos] = bf16(Wk2[2kb+(cc>>3)][((cc&7)*8+j)*64+f]),
//      cc = pos ^ (f&15).  Pre-swizzled so k_ctr staging is linear. ----
__global__ __launch_bounds__(256) void k_prep2(const float* __restrict__ Wk2,
                                               unsigned short* __restrict__ Wk2F) {
  const int kb = blockIdx.x;
  const int t = threadIdx.x;
  const int f = t & 63, pp = t >> 6;
#pragma unroll
  for (int q = 0; q < 4; ++q) {
    int pos = pp * 4 + q;
    int cc = pos ^ (f & 15);
    int kw = 2 * kb + (cc >> 3);
    int dbase = (cc & 7) * 8;
    short8 v;
#pragma unroll
    for (int j = 0; j < 8; ++j)
      v[j] = bf16s(Wk2[(size_t)kw * 4096 + (dbase + j) * 64 + f]);
    *(short8*)((char*)Wk2F + (size_t)kb * 16384 + f * 256 + pos * 16) = v;
  }
}

// ---------------- Y(N,64) = X(N,64) @ W(64,64) ----------------
__global__ __launch_bounds__(256) void k_linear64(const float* __restrict__ X,
                                                  const float* __restrict__ W,
                                                  float* __restrict__ Y, int N) {
  __shared__ float Ws[64 * 64];
  __shared__ float Xs[4][65];
  const int t = threadIdx.x;
  for (int i = t; i < 4096; i += 256) Ws[i] = W[i];
  const int r = t >> 6, f = t & 63;
  const int n = blockIdx.x * 4 + r;
  Xs[r][f] = (n < N) ? X[n * 64 + f] : 0.f;
  __syncthreads();
  if (n < N) {
    float s = 0.f;
#pragma unroll
    for (int d = 0; d < 64; ++d) s += Xs[r][d] * Ws[d * 64 + f];
    Y[n * 64 + f] = s;
  }
}

// ---------------- attention scores + segment max ----------------
__global__ __launch_bounds__(256) void k_score(const float* __restrict__ q,
                                               const float* __restrict__ kb,
                                               const float* __restrict__ ea_mf,
                                               const int* __restrict__ ei_mf,
                                               const float* __restrict__ We,
                                               float* __restrict__ score,
                                               float* __restrict__ m) {
  const int t = threadIdx.x;
  const int e = blockIdx.x * 4 + (t >> 6);
  const int lane = t & 63;
  if (e >= EMFN) return;
  const int sm = ei_mf[e];
  const int df = ei_mf[EMFN + e];
  float ke = kb[sm * 64 + lane];
#pragma unroll
  for (int i = 0; i < 6; ++i) ke += ea_mf[e * 6 + i] * We[i * 64 + lane];
  float s = q[df * 64 + lane] * ke;
#pragma unroll
  for (int o = 32; o; o >>= 1) s += __shfl_xor(s, o, 64);
  s *= 0.125f;
  if (lane == 0) {
    score[e] = s;
    atomicMaxFloat(&m[df], s);
  }
}

// ---------------- a=exp(score-m); z += a; xc += a*v[src] ----------------
__global__ __launch_bounds__(256) void k_az(const float* __restrict__ score,
                                            const float* __restrict__ m,
                                            const int* __restrict__ ei_mf,
                                            const float* __restrict__ vb,
                                            float* __restrict__ z,
                                            float* __restrict__ xc) {
  const int t = threadIdx.x;
  const int e = blockIdx.x * 4 + (t >> 6);
  const int lane = t & 63;
  if (e >= EMFN) return;
  const int sm = ei_mf[e];
  const int df = ei_mf[EMFN + e];
  const float a = expf(score[e] - m[df]);
  if (lane == 0) atomicAdd(&z[df], a);
  atomicAdd(&xc[df * 64 + lane], a * vb[sm * 64 + lane]);
}

// ============ k_h1: edge MLP -> h1g (bf16, chunk-local cols) ============
// R1 (69,632 B): {w0s|bk0s|eas} -> BtC[512][128] -> h1sT[512][136B]
// R2 (65,536 B): h0s swz bf16
__global__ __launch_bounds__(512, 1) void k_h1(
    const float* __restrict__ ea_ff, int eoff,
    const float* __restrict__ Wk0, const float* __restrict__ bk0,
    const float* __restrict__ bk1,
    const unsigned short* __restrict__ Wk1T,   // [512 n][512 k] bf16
    unsigned short* __restrict__ h1g, long estride) {
  __shared__ __align__(16) char LDS[135168];
  char* R1 = LDS;
  char* R2 = LDS + 69632;
  const int t = threadIdx.x;
  const int w = t >> 6, lane = t & 63, half = lane >> 5;
  const int e0g = eoff + blockIdx.x * 64;

  float* w0s  = (float*)R1;            // [6][512]
  float* bk0s = (float*)(R1 + 12288);  // [512]
  float* eas  = (float*)(R1 + 14336);  // [64][6]
  for (int i = t; i < 3072; i += 512) w0s[i] = Wk0[i];
  if (t < 512) bk0s[t] = bk0[t];
  if (t < 384) {
    long g = (long)e0g * 6 + t;
    eas[t] = (g < (long)EFFN * 6) ? ea_ff[g] : 0.f;
  }
  __syncthreads();

  // h0 = relu(ea@Wk0+bk0) -> R2 swizzled bf16
  {
    int e = t >> 3, c0 = (t & 7) * 64;
    float ea[6];
#pragma unroll
    for (int i = 0; i < 6; ++i) ea[i] = eas[e * 6 + i];
#pragma unroll
    for (int s8 = 0; s8 < 8; ++s8) {
      int kbase = c0 + s8 * 8;
      float s[8];
      float4 b0 = *(const float4*)(bk0s + kbase);
      float4 b1 = *(const float4*)(bk0s + kbase + 4);
      s[0]=b0.x; s[1]=b0.y; s[2]=b0.z; s[3]=b0.w; s[4]=b1.x; s[5]=b1.y; s[6]=b1.z; s[7]=b1.w;
#pragma unroll
      for (int i = 0; i < 6; ++i) {
        float4 w0 = *(const float4*)(w0s + i * 512 + kbase);
        float4 w1 = *(const float4*)(w0s + i * 512 + kbase + 4);
        s[0] = fmaf(ea[i], w0.x, s[0]); s[1] = fmaf(ea[i], w0.y, s[1]);
        s[2] = fmaf(ea[i], w0.z, s[2]); s[3] = fmaf(ea[i], w0.w, s[3]);
        s[4] = fmaf(ea[i], w1.x, s[4]); s[5] = fmaf(ea[i], w1.y, s[5]);
        s[6] = fmaf(ea[i], w1.z, s[6]); s[7] = fmaf(ea[i], w1.w, s[7]);
      }
      short8 v;
#pragma unroll
      for (int j = 0; j < 8; ++j) v[j] = bf16s(fmaxf(s[j], 0.f));
      int slot = (kbase >> 3) ^ (e & 15);
      *(short8*)(R2 + e * 1024 + slot * 16) = v;
    }
  }
  __syncthreads();

  // h1 = relu(h0 @ Wk1 + bk1) -> h1sT[n][e] bf16
  char* BtC = R1;  // [512 n][128 B]
  {
    f32x16 acc[2][2];
#pragma unroll
    for (int m = 0; m < 2; ++m)
#pragma unroll
      for (int n = 0; n < 2; ++n)
#pragma unroll
        for (int r = 0; r < 16; ++r) acc[m][n][r] = 0.f;
    for (int kc = 0; kc < 8; ++kc) {
#pragma unroll
      for (int i = 0; i < 8; ++i) {
        int row = w * 64 + i * 8 + (lane >> 3);
        int slot = (lane & 7) ^ (row & 7);
        const char* g = (const char*)Wk1T + (size_t)row * 1024 + kc * 128 + slot * 16;
        gl_lds16(g, BtC + (w * 64 + i * 8) * 128);
      }
      __syncthreads();
#pragma unroll
      for (int ks = 0; ks < 4; ++ks) {
        short8 a[2], b[2];
#pragma unroll
        for (int m = 0; m < 2; ++m) {
          int e = (lane & 31) + 32 * m;
          int slot = ((kc * 64 + ks * 16 + half * 8) >> 3) ^ (e & 15);
          a[m] = *(const short8*)(R2 + e * 1024 + slot * 16);
        }
#pragma unroll
        for (int n = 0; n < 2; ++n) {
          int nl = w * 64 + n * 32 + (lane & 31);
          int slot = (2 * ks + half) ^ (nl & 7);
          b[n] = *(const short8*)(BtC + nl * 128 + slot * 16);
        }
#pragma unroll
        for (int m = 0; m < 2; ++m)
#pragma unroll
          for (int n = 0; n < 2; ++n)
            acc[m][n] = __builtin_amdgcn_mfma_f32_32x32x16_bf16(a[m], b[n], acc[m][n], 0, 0, 0);
      }
      __syncthreads();
    }
#pragma unroll
    for (int n = 0; n < 2; ++n) {
      int nl = w * 64 + n * 32 + (lane & 31);
      float b1 = bk1[nl];
#pragma unroll
      for (int m = 0; m < 2; ++m) {
#pragma unroll
        for (int rq = 0; rq < 4; ++rq) {
          int e0 = 32 * m + 8 * rq + 4 * half;
          unsigned short u0 = (unsigned short)bf16s(fmaxf(acc[m][n][rq * 4 + 0] + b1, 0.f));
          unsigned short u1 = (unsigned short)bf16s(fmaxf(acc[m][n][rq * 4 + 1] + b1, 0.f));
          unsigned short u2 = (unsigned short)bf16s(fmaxf(acc[m][n][rq * 4 + 2] + b1, 0.f));
          unsigned short u3 = (unsigned short)bf16s(fmaxf(acc[m][n][rq * 4 + 3] + b1, 0.f));
          uint2 val = make_uint2((unsigned)u0 | ((unsigned)u1 << 16),
                                 (unsigned)u2 | ((unsigned)u3 << 16));
          *(uint2*)(R1 + nl * 136 + e0 * 2) = val;
        }
      }
    }
    __syncthreads();
  }

  // dump h1sT -> h1g (coalesced 128B rows), chunk-local col base
  {
    const long e0c = (long)blockIdx.x * 64;
#pragma unroll 4
    for (int it = 0; it < 32; ++it) {
      int row = it * 16 + (t >> 5);
      unsigned v = *(const unsigned*)(R1 + row * 136 + (t & 31) * 4);
      *(unsigned*)((char*)h1g + ((size_t)row * estride + e0c) * 2 + (t & 31) * 4) = v;
    }
  }
}

// ============ k_ctr: contraction, 256-edge tiles, MFMA-bound ============
// LDS 69,632 B: xs[256][72] bf16 (36,864) | B dbuf 2x16,384
__global__ __launch_bounds__(512, 2) void k_ctr(
    const float* __restrict__ x_flow, const int* __restrict__ ei_ff,
    const unsigned short* __restrict__ Wk2F,   // [256 kb][16KB pre-swizzled]
    const unsigned short* __restrict__ h1g,    // [512][estride] chunk-local
    long estride, int eoff,
    float* __restrict__ aggr, float* __restrict__ xsum) {
  __shared__ __align__(16) char L[69632];
  unsigned short* xs = (unsigned short*)L;     // [256][72]
  char* Bb = L + 36864;                        // 2 x 16384
  const int t = threadIdx.x;
  const int w = t >> 6, lane = t & 63, half = lane >> 5;
  const int eg4 = w >> 1;   // e-group 0..3 (64 edges each)
  const int fg = w & 1;     // f-group 0..1 (32 f each)
  const int e0t = eoff + blockIdx.x * 256;
  const long bl256 = (long)blockIdx.x * 256;

  // ---- stage xs (bf16) + xsum atomics ----
  {
    int row = t >> 1, c0 = (t & 1) * 32;
    int eg = e0t + row;
    bool valid = eg < EFFN;
    int src = valid ? ei_ff[eg] : 0;
    int dst = valid ? ei_ff[EFFN + eg] : 0;
    float4 v[8];
#pragma unroll
    for (int q = 0; q < 8; ++q)
      v[q] = valid ? *(const float4*)(x_flow + (size_t)src * 64 + c0 + q * 4)
                   : make_float4(0.f, 0.f, 0.f, 0.f);
    const float* vf = (const float*)v;
#pragma unroll
    for (int q = 0; q < 4; ++q) {
      short8 u;
#pragma unroll
      for (int j = 0; j < 8; ++j) u[j] = bf16s(vf[q * 8 + j]);
      *(short8*)(xs + row * 72 + c0 + q * 8) = u;
    }
    if (valid) {
#pragma unroll
      for (int q = 0; q < 8; ++q) {
        atomicAdd(&xsum[dst * 64 + c0 + q * 4 + 0], v[q].x);
        atomicAdd(&xsum[dst * 64 + c0 + q * 4 + 1], v[q].y);
        atomicAdd(&xsum[dst * 64 + c0 + q * 4 + 2], v[q].z);
        atomicAdd(&xsum[dst * 64 + c0 + q * 4 + 3], v[q].w);
      }
    }
  }
  __syncthreads();

  // ---- x fragments -> f32 registers: xr[mi][db][j], d = db*16 + 8*half + j
  float xr[2][4][8];
#pragma unroll
  for (int mi = 0; mi < 2; ++mi) {
    int e = eg4 * 64 + mi * 32 + (lane & 31);
#pragma unroll
    for (int db = 0; db < 4; ++db) {
      short8 xv = *(const short8*)(xs + e * 72 + db * 16 + 8 * half);
#pragma unroll
      for (int j = 0; j < 8; ++j)
        xr[mi][db][j] = __uint_as_float(((unsigned)(unsigned short)xv[j]) << 16);
    }
  }

  f32x16 acc[2];
#pragma unroll
  for (int mi = 0; mi < 2; ++mi)
#pragma unroll
    for (int r = 0; r < 16; ++r) acc[mi][r] = 0.f;

  // ---- prologue: B(0) + hm(0) ----
  {
    const char* g = (const char*)Wk2F;
    gl_lds16(g + (w * 2 + 0) * 1024 + lane * 16, Bb + (w * 2 + 0) * 1024);
    gl_lds16(g + (w * 2 + 1) * 1024 + lane * 16, Bb + (w * 2 + 1) * 1024);
  }
  unsigned short hc0, hc1, hc2, hc3;
  {
    const unsigned short* h0p = h1g + bl256 + eg4 * 64 + (lane & 31);
    hc0 = h0p[0]; hc1 = h0p[32];
    hc2 = h0p[estride]; hc3 = h0p[estride + 32];
  }

  for (int kb = 0; kb < 256; ++kb) {
    asm volatile("s_waitcnt vmcnt(0)" ::: "memory");
    __builtin_amdgcn_s_barrier();
    unsigned short hn0 = hc0, hn1 = hc1, hn2 = hc2, hn3 = hc3;
    int nb = kb + 1;
    if (nb < 256) {
      char* dstB = Bb + (nb & 1) * 16384;
      const char* g = (const char*)Wk2F + (size_t)nb * 16384;
      gl_lds16(g + (w * 2 + 0) * 1024 + lane * 16, dstB + (w * 2 + 0) * 1024);
      gl_lds16(g + (w * 2 + 1) * 1024 + lane * 16, dstB + (w * 2 + 1) * 1024);
      const unsigned short* h0p =
          h1g + (size_t)(2 * nb) * estride + bl256 + eg4 * 64 + (lane & 31);
      hn0 = h0p[0]; hn1 = h0p[32];
      hn2 = h0p[estride]; hn3 = h0p[estride + 32];
    }
    float hm[2][2];
    hm[0][0] = __uint_as_float((unsigned)hc0 << 16);
    hm[1][0] = __uint_as_float((unsigned)hc1 << 16);
    hm[0][1] = __uint_as_float((unsigned)hc2 << 16);
    hm[1][1] = __uint_as_float((unsigned)hc3 << 16);
    const char* cur = Bb + (kb & 1) * 16384;
    const int f = fg * 32 + (lane & 31);
    __builtin_amdgcn_s_setprio(1);
#pragma unroll
    for (int s = 0; s < 8; ++s) {
      const int p = s >> 2, db = s & 3;
      int pos = (2 * s + half) ^ (f & 15);
      short8 b = *(const short8*)(cur + f * 256 + pos * 16);
#pragma unroll
      for (int mi = 0; mi < 2; ++mi) {
        float h = hm[mi][p];
        short8 a;
#pragma unroll
        for (int j = 0; j < 8; ++j) a[j] = bf16s(h * xr[mi][db][j]);
        acc[mi] = __builtin_amdgcn_mfma_f32_32x32x16_bf16(a, b, acc[mi], 0, 0, 0);
      }
    }
    __builtin_amdgcn_s_setprio(0);
    hc0 = hn0; hc1 = hn1; hc2 = hn2; hc3 = hn3;
  }

  // ---- epilogue: segment-sum atomics (waves own disjoint outputs) ----
#pragma unroll
  for (int mi = 0; mi < 2; ++mi)
#pragma unroll
    for (int r = 0; r < 16; ++r) {
      int e_loc = eg4 * 64 + mi * 32 + (r & 3) + 8 * (r >> 2) + 4 * half;
      int eg = e0t + e_loc;
      int f = fg * 32 + (lane & 31);
      if (eg < EFFN)
        atomicAdd(&aggr[(size_t)ei_ff[EFFN + eg] * 64 + f], acc[mi][r]);
    }
}

// ---------------- final: Wroot/Wo/bk2 applies, FiLM, silu ----------------
__global__ __launch_bounds__(256) void k_final(
    const float* __restrict__ x_flow, const float* __restrict__ aggr,
    const float* __restrict__ xc, const float* __restrict__ z,
    const float* __restrict__ xsum, const float* __restrict__ bk2,
    const float* __restrict__ Wroot, const float* __restrict__ broot,
    const float* __restrict__ Wo, const float* __restrict__ bo,
    const float* __restrict__ tau, const float* __restrict__ Wt1,
    const float* __restrict__ bt1, const float* __restrict__ Wt2,
    const float* __restrict__ bt2, float* __restrict__ out) {
  __shared__ float WoS[4096], WrS[4096], B2S[4096], ssS[128], tembS[64];
  __shared__ float xcnS[4][65], xfS[4][65], xsS[4][65];
  const int t = threadIdx.x;
  for (int i = t; i < 4096; i += 256) { WoS[i] = Wo[i]; WrS[i] = Wroot[i]; B2S[i] = bk2[i]; }
  if (t < 64) {
    float y = tau[0] * Wt1[t] + bt1[t];
    tembS[t] = y / (1.f + expf(-y));
  }
  __syncthreads();
  if (t < 128) {
    float s = bt2[t];
#pragma unroll
    for (int d = 0; d < 64; ++d) s += tembS[d] * Wt2[d * 128 + t];
    ssS[t] = s;
  }
  const int r = t >> 6, f = t & 63;
  const int n = blockIdx.x * 4 + r;
  if (n < NFLOW) {
    float zr = z[n];
    xcnS[r][f] = xc[n * 64 + f] / (zr + 1e-9f);
    xfS[r][f] = x_flow[n * 64 + f];
    xsS[r][f] = xsum[n * 64 + f];
  }
  __syncthreads();
  if (n < NFLOW) {
    float cross = bo[f], root = broot[f], rb = 0.f;
#pragma unroll
    for (int d = 0; d < 64; ++d) {
      cross += xcnS[r][d] * WoS[d * 64 + f];
      root += xfS[r][d] * WrS[d * 64 + f];
      rb += xsS[r][d] * B2S[d * 64 + f];
    }
    float g = root + rb + aggr[n * 64 + f] + cross;
    g = fmaxf(g, 0.f);
    float y = g * (1.f + ssS[f]) + ssS[64 + f];
    out[n * 64 + f] = y / (1.f + expf(-y));
  }
}

extern "C" void kernel_launch(void* const* d_in, const int* in_sizes, int n_in,
                              void* d_out, int out_size, void* d_ws, size_t ws_size,
                              hipStream_t stream) {
  const float* x_flow = (const float*)d_in[0];
  const float* x_memb = (const float*)d_in[1];
  const float* ea_ff  = (const float*)d_in[2];
  const float* ea_mf  = (const float*)d_in[3];
  const float* tau    = (const float*)d_in[4];
  const int*   ei_ff  = (const int*)d_in[5];
  const int*   ei_mf  = (const int*)d_in[6];
  const float* Wk0 = (const float*)d_in[7],  *bk0 = (const float*)d_in[8];
  const float* Wk1 = (const float*)d_in[9],  *bk1 = (const float*)d_in[10];
  const float* Wk2 = (const float*)d_in[11], *bk2 = (const float*)d_in[12];
  const float* Wroot = (const float*)d_in[13], *broot = (const float*)d_in[14];
  const float* Wq = (const float*)d_in[15];
  const float* Wkk = (const float*)d_in[16];
  const float* Wv = (const float*)d_in[17];
  const float* We = (const float*)d_in[18];
  const float* Wo = (const float*)d_in[19], *bo = (const float*)d_in[20];
  const float* Wt1 = (const float*)d_in[21], *bt1 = (const float*)d_in[22];
  const float* Wt2 = (const float*)d_in[23], *bt2 = (const float*)d_in[24];

  float* ws = (float*)d_ws;
  float* xc    = ws;                    // NF*64
  float* aggr  = xc + NFLOW * 64;       // NF*64
  float* m     = aggr + NFLOW * 64;     // NF
  float* z     = m + NFLOW;             // NF
  float* score = z + NFLOW;             // EMF
  float* q     = score + EMFN;          // NF*64
  float* kb    = q + NFLOW * 64;        // NM*64
  float* vb    = kb + NMEMB * 64;       // NM*64
  float* xsum  = vb + NMEMB * 64;       // NF*64
  unsigned short* Wk1T = (unsigned short*)(xsum + NFLOW * 64);  // 512*512 bf16
  unsigned short* Wk2F = Wk1T + 512 * 512;                      // 256*8192 bf16
  unsigned short* h1g  = Wk2F + 256 * 8192;                     // chunked
  float* out = (float*)d_out;

  // adaptive h1 chunk size from ws_size
  size_t used = (size_t)((char*)h1g - (char*)d_ws);
  size_t freeb = ws_size > used ? ws_size - used : 0;
  long che = (long)(freeb / (512 * 2));   // edges that fit
  che = (che / 256) * 256;
  if (che > PAD_E) che = PAD_E;
  if (che < 256) che = 256;

  k_init<<<(NFLOW * 64 + 255) / 256, 256, 0, stream>>>(xc, aggr, m, z, xsum);
  {
    dim3 g1(8, 8);
    k_transpose<<<g1, 256, 0, stream>>>(Wk1, Wk1T, 512, 512);
    k_prep2<<<256, 256, 0, stream>>>(Wk2, Wk2F);
  }
  k_linear64<<<(NFLOW + 3) / 4, 256, 0, stream>>>(x_flow, Wq, q, NFLOW);
  k_linear64<<<(NMEMB + 3) / 4, 256, 0, stream>>>(x_memb, Wkk, kb, NMEMB);
  k_linear64<<<(NMEMB + 3) / 4, 256, 0, stream>>>(x_memb, Wv, vb, NMEMB);
  k_score<<<EMFN / 4, 256, 0, stream>>>(q, kb, ea_mf, ei_mf, We, score, m);
  k_az<<<EMFN / 4, 256, 0, stream>>>(score, m, ei_mf, vb, z, xc);

  for (long eoff = 0; eoff < PAD_E; eoff += che) {
    long ce = PAD_E - eoff; if (ce > che) ce = che;
    k_h1<<<(int)(ce / 64), 512, 0, stream>>>(ea_ff, (int)eoff, Wk0, bk0, bk1,
                                             Wk1T, h1g, che);
    k_ctr<<<(int)(ce / 256), 512, 0, stream>>>(x_flow, ei_ff, Wk2F, h1g, che,
                                               (int)eoff, aggr, xsum);
  }

  k_final<<<(NFLOW + 3) / 4, 256, 0, stream>>>(x_flow, aggr, xc, z, xsum, bk2,
                                               Wroot, broot, Wo, bo, tau, Wt1, bt1,
                                               Wt2, bt2, out);
}

// Round 8
// 1067.082 us; speedup vs baseline: 1.5965x; 1.3376x over previous
//
#include <hip/hip_runtime.h>
#include <hip/hip_bf16.h>

#define NFLOW 20000
#define NMEMB 5000
#define EFFN  100000
#define EMFN  80000
#define PAD_E 100352  // 392 tiles of 256 / 1568 tiles of 64

using short8 = __attribute__((ext_vector_type(8))) short;
using f32x16 = __attribute__((ext_vector_type(16))) float;

__device__ __forceinline__ short bf16s(float f) {
  __hip_bfloat16 h = __float2bfloat16(f);
  return *reinterpret_cast<short*>(&h);
}

__device__ __forceinline__ void gl_lds16(const void* g, void* l) {
  __builtin_amdgcn_global_load_lds(
      (const __attribute__((address_space(1))) unsigned int*)g,
      (__attribute__((address_space(3))) unsigned int*)l, 16, 0, 0);
}

__device__ __forceinline__ void atomicMaxFloat(float* addr, float val) {
  int* ai = (int*)addr;
  int old = __float_as_int(*addr);
  while (__int_as_float(old) < val) {
    int assumed = old;
    old = atomicCAS(ai, assumed, __float_as_int(val));
    if (old == assumed) break;
  }
}

// ---------------- init ----------------
__global__ __launch_bounds__(256) void k_init(float* __restrict__ xc,
                                              float* __restrict__ aggr,
                                              float* __restrict__ m,
                                              float* __restrict__ z,
                                              float* __restrict__ xsum) {
  int i = blockIdx.x * 256 + threadIdx.x;
  if (i < NFLOW * 64) { xc[i] = 0.f; aggr[i] = 0.f; xsum[i] = 0.f; }
  if (i < NFLOW) { m[i] = __int_as_float(0xff800000); z[i] = 0.f; }
}

// ------------- transpose+cvt: out[c*R+r] = bf16(in[r*C+c]) (for Wk1T) -------
__global__ __launch_bounds__(256) void k_transpose(const float* __restrict__ in,
                                                   unsigned short* __restrict__ out,
                                                   int R, int C) {
  __shared__ unsigned short tile[64][66];
  const int t = threadIdx.x;
  const int r0 = blockIdx.x * 64, c0 = blockIdx.y * 64;
  {
    int r = t >> 2;
    int cb = (t & 3) * 16;
#pragma unroll
    for (int q = 0; q < 4; ++q) {
      float4 v = *(const float4*)(in + (size_t)(r0 + r) * C + c0 + cb + q * 4);
      tile[r][cb + q * 4 + 0] = (unsigned short)bf16s(v.x);
      tile[r][cb + q * 4 + 1] = (unsigned short)bf16s(v.y);
      tile[r][cb + q * 4 + 2] = (unsigned short)bf16s(v.z);
      tile[r][cb + q * 4 + 3] = (unsigned short)bf16s(v.w);
    }
  }
  __syncthreads();
  {
    int c = t >> 2;
    int rb = (t & 3) * 16;
#pragma unroll
    for (int q = 0; q < 4; ++q) {
      int r = rb + q * 4;
      ushort4 v = make_ushort4(tile[r][c], tile[r + 1][c], tile[r + 2][c], tile[r + 3][c]);
      *(ushort4*)(out + (size_t)(c0 + c) * R + r0 + r) = v;
    }
  }
}

// ---- k_prep2: Wk2F[kb][f][pos] = bf16(Wk2[2kb+(cc>>3)][((cc&7)*8+j)*64+f]),
//      cc = pos ^ (f&15).  Pre-swizzled so k_ctr staging is linear. ----
__global__ __launch_bounds__(256) void k_prep2(const float* __restrict__ Wk2,
                                               unsigned short* __restrict__ Wk2F) {
  const int kb = blockIdx.x;
  const int t = threadIdx.x;
  const int f = t & 63, pp = t >> 6;
#pragma unroll
  for (int q = 0; q < 4; ++q) {
    int pos = pp * 4 + q;
    int cc = pos ^ (f & 15);
    int kw = 2 * kb + (cc >> 3);
    int dbase = (cc & 7) * 8;
    short8 v;
#pragma unroll
    for (int j = 0; j < 8; ++j)
      v[j] = bf16s(Wk2[(size_t)kw * 4096 + (dbase + j) * 64 + f]);
    *(short8*)((char*)Wk2F + (size_t)kb * 16384 + f * 256 + pos * 16) = v;
  }
}

// ---------------- Y(N,64) = X(N,64) @ W(64,64) ----------------
__global__ __launch_bounds__(256) void k_linear64(const float* __restrict__ X,
                                                  const float* __restrict__ W,
                                                  float* __restrict__ Y, int N) {
  __shared__ float Ws[64 * 64];
  __shared__ float Xs[4][65];
  const int t = threadIdx.x;
  for (int i = t; i < 4096; i += 256) Ws[i] = W[i];
  const int r = t >> 6, f = t & 63;
  const int n = blockIdx.x * 4 + r;
  Xs[r][f] = (n < N) ? X[n * 64 + f] : 0.f;
  __syncthreads();
  if (n < N) {
    float s = 0.f;
#pragma unroll
    for (int d = 0; d < 64; ++d) s += Xs[r][d] * Ws[d * 64 + f];
    Y[n * 64 + f] = s;
  }
}

// ---------------- attention scores + segment max ----------------
__global__ __launch_bounds__(256) void k_score(const float* __restrict__ q,
                                               const float* __restrict__ kb,
                                               const float* __restrict__ ea_mf,
                                               const int* __restrict__ ei_mf,
                                               const float* __restrict__ We,
                                               float* __restrict__ score,
                                               float* __restrict__ m) {
  const int t = threadIdx.x;
  const int e = blockIdx.x * 4 + (t >> 6);
  const int lane = t & 63;
  if (e >= EMFN) return;
  const int sm = ei_mf[e];
  const int df = ei_mf[EMFN + e];
  float ke = kb[sm * 64 + lane];
#pragma unroll
  for (int i = 0; i < 6; ++i) ke += ea_mf[e * 6 + i] * We[i * 64 + lane];
  float s = q[df * 64 + lane] * ke;
#pragma unroll
  for (int o = 32; o; o >>= 1) s += __shfl_xor(s, o, 64);
  s *= 0.125f;
  if (lane == 0) {
    score[e] = s;
    atomicMaxFloat(&m[df], s);
  }
}

// ---------------- a=exp(score-m); z += a; xc += a*v[src] ----------------
__global__ __launch_bounds__(256) void k_az(const float* __restrict__ score,
                                            const float* __restrict__ m,
                                            const int* __restrict__ ei_mf,
                                            const float* __restrict__ vb,
                                            float* __restrict__ z,
                                            float* __restrict__ xc) {
  const int t = threadIdx.x;
  const int e = blockIdx.x * 4 + (t >> 6);
  const int lane = t & 63;
  if (e >= EMFN) return;
  const int sm = ei_mf[e];
  const int df = ei_mf[EMFN + e];
  const float a = expf(score[e] - m[df]);
  if (lane == 0) atomicAdd(&z[df], a);
  atomicAdd(&xc[df * 64 + lane], a * vb[sm * 64 + lane]);
}

// ============ k_h1: edge MLP -> h1p (u32-packed bf16 pairs) ============
// R1 (69,632 B): {w0s|bk0s|eas} -> BtC[512][128] -> h1sT[512][136B]
// R2 (65,536 B): h0s swz bf16
__global__ __launch_bounds__(512, 1) void k_h1(
    const float* __restrict__ ea_ff, int eoff,
    const float* __restrict__ Wk0, const float* __restrict__ bk0,
    const float* __restrict__ bk1,
    const unsigned short* __restrict__ Wk1T,   // [512 n][512 k] bf16
    unsigned int* __restrict__ h1p, long estride) {
  __shared__ __align__(16) char LDS[135168];
  char* R1 = LDS;
  char* R2 = LDS + 69632;
  const int t = threadIdx.x;
  const int w = t >> 6, lane = t & 63, half = lane >> 5;
  const int e0g = eoff + blockIdx.x * 64;

  float* w0s  = (float*)R1;            // [6][512]
  float* bk0s = (float*)(R1 + 12288);  // [512]
  float* eas  = (float*)(R1 + 14336);  // [64][6]
  for (int i = t; i < 3072; i += 512) w0s[i] = Wk0[i];
  if (t < 512) bk0s[t] = bk0[t];
  if (t < 384) {
    long g = (long)e0g * 6 + t;
    eas[t] = (g < (long)EFFN * 6) ? ea_ff[g] : 0.f;
  }
  __syncthreads();

  // h0 = relu(ea@Wk0+bk0) -> R2 swizzled bf16
  {
    int e = t >> 3, c0 = (t & 7) * 64;
    float ea[6];
#pragma unroll
    for (int i = 0; i < 6; ++i) ea[i] = eas[e * 6 + i];
#pragma unroll
    for (int s8 = 0; s8 < 8; ++s8) {
      int kbase = c0 + s8 * 8;
      float s[8];
      float4 b0 = *(const float4*)(bk0s + kbase);
      float4 b1 = *(const float4*)(bk0s + kbase + 4);
      s[0]=b0.x; s[1]=b0.y; s[2]=b0.z; s[3]=b0.w; s[4]=b1.x; s[5]=b1.y; s[6]=b1.z; s[7]=b1.w;
#pragma unroll
      for (int i = 0; i < 6; ++i) {
        float4 w0 = *(const float4*)(w0s + i * 512 + kbase);
        float4 w1 = *(const float4*)(w0s + i * 512 + kbase + 4);
        s[0] = fmaf(ea[i], w0.x, s[0]); s[1] = fmaf(ea[i], w0.y, s[1]);
        s[2] = fmaf(ea[i], w0.z, s[2]); s[3] = fmaf(ea[i], w0.w, s[3]);
        s[4] = fmaf(ea[i], w1.x, s[4]); s[5] = fmaf(ea[i], w1.y, s[5]);
        s[6] = fmaf(ea[i], w1.z, s[6]); s[7] = fmaf(ea[i], w1.w, s[7]);
      }
      short8 v;
#pragma unroll
      for (int j = 0; j < 8; ++j) v[j] = bf16s(fmaxf(s[j], 0.f));
      int slot = (kbase >> 3) ^ (e & 15);
      *(short8*)(R2 + e * 1024 + slot * 16) = v;
    }
  }
  __syncthreads();

  // h1 = relu(h0 @ Wk1 + bk1) -> h1sT[n][e] bf16
  char* BtC = R1;  // [512 n][128 B]
  {
    f32x16 acc[2][2];
#pragma unroll
    for (int m = 0; m < 2; ++m)
#pragma unroll
      for (int n = 0; n < 2; ++n)
#pragma unroll
        for (int r = 0; r < 16; ++r) acc[m][n][r] = 0.f;
    for (int kc = 0; kc < 8; ++kc) {
#pragma unroll
      for (int i = 0; i < 8; ++i) {
        int row = w * 64 + i * 8 + (lane >> 3);
        int slot = (lane & 7) ^ (row & 7);
        const char* g = (const char*)Wk1T + (size_t)row * 1024 + kc * 128 + slot * 16;
        gl_lds16(g, BtC + (w * 64 + i * 8) * 128);
      }
      __syncthreads();
#pragma unroll
      for (int ks = 0; ks < 4; ++ks) {
        short8 a[2], b[2];
#pragma unroll
        for (int m = 0; m < 2; ++m) {
          int e = (lane & 31) + 32 * m;
          int slot = ((kc * 64 + ks * 16 + half * 8) >> 3) ^ (e & 15);
          a[m] = *(const short8*)(R2 + e * 1024 + slot * 16);
        }
#pragma unroll
        for (int n = 0; n < 2; ++n) {
          int nl = w * 64 + n * 32 + (lane & 31);
          int slot = (2 * ks + half) ^ (nl & 7);
          b[n] = *(const short8*)(BtC + nl * 128 + slot * 16);
        }
#pragma unroll
        for (int m = 0; m < 2; ++m)
#pragma unroll
          for (int n = 0; n < 2; ++n)
            acc[m][n] = __builtin_amdgcn_mfma_f32_32x32x16_bf16(a[m], b[n], acc[m][n], 0, 0, 0);
      }
      __syncthreads();
    }
#pragma unroll
    for (int n = 0; n < 2; ++n) {
      int nl = w * 64 + n * 32 + (lane & 31);
      float b1 = bk1[nl];
#pragma unroll
      for (int m = 0; m < 2; ++m) {
#pragma unroll
        for (int rq = 0; rq < 4; ++rq) {
          int e0 = 32 * m + 8 * rq + 4 * half;
          unsigned short u0 = (unsigned short)bf16s(fmaxf(acc[m][n][rq * 4 + 0] + b1, 0.f));
          unsigned short u1 = (unsigned short)bf16s(fmaxf(acc[m][n][rq * 4 + 1] + b1, 0.f));
          unsigned short u2 = (unsigned short)bf16s(fmaxf(acc[m][n][rq * 4 + 2] + b1, 0.f));
          unsigned short u3 = (unsigned short)bf16s(fmaxf(acc[m][n][rq * 4 + 3] + b1, 0.f));
          uint2 val = make_uint2((unsigned)u0 | ((unsigned)u1 << 16),
                                 (unsigned)u2 | ((unsigned)u3 << 16));
          *(uint2*)(R1 + nl * 136 + e0 * 2) = val;
        }
      }
    }
    __syncthreads();
  }

  // dump h1sT -> h1p packed: h1p[rp][e] = h1[2rp]|h1[2rp+1]<<16
  {
    const long e0c = (long)blockIdx.x * 64;
#pragma unroll 4
    for (int it = 0; it < 32; ++it) {
      int idx = it * 512 + t;
      int rp = idx >> 6;
      int e = idx & 63;
      unsigned lo = *(const unsigned short*)(R1 + (2 * rp) * 136 + e * 2);
      unsigned hi = *(const unsigned short*)(R1 + (2 * rp + 1) * 136 + e * 2);
      h1p[(size_t)rp * estride + e0c + e] = lo | (hi << 16);
    }
  }
}

// ============ k_ctr: contraction, 256-edge tiles, ring-3, 1 barrier/iter ====
// LDS = ring 3 x 16KB only.  Wave w owns edges w*32..w*32+31, all 64 f (n=2).
__global__ __launch_bounds__(512, 4) void k_ctr(
    const float* __restrict__ x_flow, const int* __restrict__ ei_ff,
    const unsigned short* __restrict__ Wk2F,   // [256 kb][16KB pre-swizzled]
    const unsigned int* __restrict__ h1p,      // [256][estride] u32 packed
    long estride, int eoff,
    float* __restrict__ aggr, float* __restrict__ xsum) {
  __shared__ __align__(16) char L[49152];
  const int t = threadIdx.x;
  const int w = t >> 6, lane = t & 63, half = lane >> 5;
  const int e0t = eoff + blockIdx.x * 256;
  const long bl256 = (long)blockIdx.x * 256;
  const int el = w * 32 + (lane & 31);
  const int eg = e0t + el;
  const bool valid = eg < EFFN;
  const int src = valid ? ei_ff[eg] : 0;
  const int dst = valid ? ei_ff[EFFN + eg] : 0;

  // ---- gather x -> f32 registers; xsum atomics from same values ----
  float xf[4][8];
#pragma unroll
  for (int db = 0; db < 4; ++db) {
    float4 v0 = valid ? *(const float4*)(x_flow + (size_t)src * 64 + db * 16 + 8 * half)
                      : make_float4(0.f, 0.f, 0.f, 0.f);
    float4 v1 = valid ? *(const float4*)(x_flow + (size_t)src * 64 + db * 16 + 8 * half + 4)
                      : make_float4(0.f, 0.f, 0.f, 0.f);
    xf[db][0] = v0.x; xf[db][1] = v0.y; xf[db][2] = v0.z; xf[db][3] = v0.w;
    xf[db][4] = v1.x; xf[db][5] = v1.y; xf[db][6] = v1.z; xf[db][7] = v1.w;
    if (valid) {
      int d0 = db * 16 + 8 * half;
#pragma unroll
      for (int j = 0; j < 8; ++j)
        atomicAdd(&xsum[(size_t)dst * 64 + d0 + j], xf[db][j]);
    }
  }

  // ---- prologue: h1(0), stage B(0), B(1) ----
  unsigned int hc = h1p[bl256 + el];
  {
    const char* g0 = (const char*)Wk2F;
    gl_lds16(g0 + (w * 2 + 0) * 1024 + lane * 16, L + (w * 2 + 0) * 1024);
    gl_lds16(g0 + (w * 2 + 1) * 1024 + lane * 16, L + (w * 2 + 1) * 1024);
    const char* g1 = (const char*)Wk2F + 16384;
    gl_lds16(g1 + (w * 2 + 0) * 1024 + lane * 16, L + 16384 + (w * 2 + 0) * 1024);
    gl_lds16(g1 + (w * 2 + 1) * 1024 + lane * 16, L + 16384 + (w * 2 + 1) * 1024);
  }
  asm volatile("s_waitcnt vmcnt(2)" ::: "memory");  // tile0 (and hc) retired

  f32x16 acc[2];
#pragma unroll
  for (int n = 0; n < 2; ++n)
#pragma unroll
    for (int r = 0; r < 16; ++r) acc[n][r] = 0.f;

  for (int kb = 0; kb < 256; ++kb) {
    __builtin_amdgcn_s_barrier();
    // issue next h1 FIRST, then next-next B stage (ordering keeps depth-2)
    unsigned int hn = hc;
    if (kb + 1 < 256)
      hn = h1p[(size_t)(kb + 1) * estride + bl256 + el];
    if (kb + 2 < 256) {
      char* dstB = L + ((kb + 2) % 3) * 16384;
      const char* g = (const char*)Wk2F + (size_t)(kb + 2) * 16384;
      gl_lds16(g + (w * 2 + 0) * 1024 + lane * 16, dstB + (w * 2 + 0) * 1024);
      gl_lds16(g + (w * 2 + 1) * 1024 + lane * 16, dstB + (w * 2 + 1) * 1024);
    }
    const char* cur = L + (kb % 3) * 16384;
    const float hm0 = __uint_as_float(hc << 16);
    const float hm1 = __uint_as_float(hc & 0xffff0000u);
    __builtin_amdgcn_s_setprio(1);
#pragma unroll
    for (int s = 0; s < 8; ++s) {
      const int db = s & 3;
      const float h = (s >> 2) ? hm1 : hm0;
      short8 a;
#pragma unroll
      for (int j = 0; j < 8; ++j) a[j] = bf16s(h * xf[db][j]);
#pragma unroll
      for (int n = 0; n < 2; ++n) {
        const int f = n * 32 + (lane & 31);
        const int pos = (2 * s + half) ^ (f & 15);
        short8 b = *(const short8*)(cur + f * 256 + pos * 16);
        acc[n] = __builtin_amdgcn_mfma_f32_32x32x16_bf16(a, b, acc[n], 0, 0, 0);
      }
    }
    __builtin_amdgcn_s_setprio(0);
    hc = hn;  // compiler waits here for h1(kb+1) -> retires glds(kb+1) too
  }

  // ---- epilogue: segment-sum atomics (waves own disjoint outputs) ----
#pragma unroll
  for (int n = 0; n < 2; ++n)
#pragma unroll
    for (int r = 0; r < 16; ++r) {
      int e_loc = w * 32 + (r & 3) + 8 * (r >> 2) + 4 * half;
      int eg2 = e0t + e_loc;
      int f = n * 32 + (lane & 31);
      if (eg2 < EFFN)
        atomicAdd(&aggr[(size_t)ei_ff[EFFN + eg2] * 64 + f], acc[n][r]);
    }
}

// ---------------- final: Wroot/Wo/bk2 applies, FiLM, silu ----------------
__global__ __launch_bounds__(256) void k_final(
    const float* __restrict__ x_flow, const float* __restrict__ aggr,
    const float* __restrict__ xc, const float* __restrict__ z,
    const float* __restrict__ xsum, const float* __restrict__ bk2,
    const float* __restrict__ Wroot, const float* __restrict__ broot,
    const float* __restrict__ Wo, const float* __restrict__ bo,
    const float* __restrict__ tau, const float* __restrict__ Wt1,
    const float* __restrict__ bt1, const float* __restrict__ Wt2,
    const float* __restrict__ bt2, float* __restrict__ out) {
  __shared__ float WoS[4096], WrS[4096], B2S[4096], ssS[128], tembS[64];
  __shared__ float xcnS[4][65], xfS[4][65], xsS[4][65];
  const int t = threadIdx.x;
  for (int i = t; i < 4096; i += 256) { WoS[i] = Wo[i]; WrS[i] = Wroot[i]; B2S[i] = bk2[i]; }
  if (t < 64) {
    float y = tau[0] * Wt1[t] + bt1[t];
    tembS[t] = y / (1.f + expf(-y));
  }
  __syncthreads();
  if (t < 128) {
    float s = bt2[t];
#pragma unroll
    for (int d = 0; d < 64; ++d) s += tembS[d] * Wt2[d * 128 + t];
    ssS[t] = s;
  }
  const int r = t >> 6, f = t & 63;
  const int n = blockIdx.x * 4 + r;
  if (n < NFLOW) {
    float zr = z[n];
    xcnS[r][f] = xc[n * 64 + f] / (zr + 1e-9f);
    xfS[r][f] = x_flow[n * 64 + f];
    xsS[r][f] = xsum[n * 64 + f];
  }
  __syncthreads();
  if (n < NFLOW) {
    float cross = bo[f], root = broot[f], rb = 0.f;
#pragma unroll
    for (int d = 0; d < 64; ++d) {
      cross += xcnS[r][d] * WoS[d * 64 + f];
      root += xfS[r][d] * WrS[d * 64 + f];
      rb += xsS[r][d] * B2S[d * 64 + f];
    }
    float g = root + rb + aggr[n * 64 + f] + cross;
    g = fmaxf(g, 0.f);
    float y = g * (1.f + ssS[f]) + ssS[64 + f];
    out[n * 64 + f] = y / (1.f + expf(-y));
  }
}

extern "C" void kernel_launch(void* const* d_in, const int* in_sizes, int n_in,
                              void* d_out, int out_size, void* d_ws, size_t ws_size,
                              hipStream_t stream) {
  const float* x_flow = (const float*)d_in[0];
  const float* x_memb = (const float*)d_in[1];
  const float* ea_ff  = (const float*)d_in[2];
  const float* ea_mf  = (const float*)d_in[3];
  const float* tau    = (const float*)d_in[4];
  const int*   ei_ff  = (const int*)d_in[5];
  const int*   ei_mf  = (const int*)d_in[6];
  const float* Wk0 = (const float*)d_in[7],  *bk0 = (const float*)d_in[8];
  const float* Wk1 = (const float*)d_in[9],  *bk1 = (const float*)d_in[10];
  const float* Wk2 = (const float*)d_in[11], *bk2 = (const float*)d_in[12];
  const float* Wroot = (const float*)d_in[13], *broot = (const float*)d_in[14];
  const float* Wq = (const float*)d_in[15];
  const float* Wkk = (const float*)d_in[16];
  const float* Wv = (const float*)d_in[17];
  const float* We = (const float*)d_in[18];
  const float* Wo = (const float*)d_in[19], *bo = (const float*)d_in[20];
  const float* Wt1 = (const float*)d_in[21], *bt1 = (const float*)d_in[22];
  const float* Wt2 = (const float*)d_in[23], *bt2 = (const float*)d_in[24];

  float* ws = (float*)d_ws;
  float* xc    = ws;                    // NF*64
  float* aggr  = xc + NFLOW * 64;       // NF*64
  float* m     = aggr + NFLOW * 64;     // NF
  float* z     = m + NFLOW;             // NF
  float* score = z + NFLOW;             // EMF
  float* q     = score + EMFN;          // NF*64
  float* kb    = q + NFLOW * 64;        // NM*64
  float* vb    = kb + NMEMB * 64;       // NM*64
  float* xsum  = vb + NMEMB * 64;       // NF*64
  unsigned short* Wk1T = (unsigned short*)(xsum + NFLOW * 64);  // 512*512 bf16
  unsigned short* Wk2F = Wk1T + 512 * 512;                      // 256*8192 bf16
  unsigned int* h1p = (unsigned int*)(Wk2F + 256 * 8192);       // [256][che] u32
  float* out = (float*)d_out;

  // adaptive h1 chunk size from ws_size (1024 B per edge)
  size_t used = (size_t)((char*)h1p - (char*)d_ws);
  size_t freeb = ws_size > used ? ws_size - used : 0;
  long che = (long)(freeb / 1024);
  che = (che / 256) * 256;
  if (che > PAD_E) che = PAD_E;
  if (che < 256) che = 256;

  k_init<<<(NFLOW * 64 + 255) / 256, 256, 0, stream>>>(xc, aggr, m, z, xsum);
  {
    dim3 g1(8, 8);
    k_transpose<<<g1, 256, 0, stream>>>(Wk1, Wk1T, 512, 512);
    k_prep2<<<256, 256, 0, stream>>>(Wk2, Wk2F);
  }
  k_linear64<<<(NFLOW + 3) / 4, 256, 0, stream>>>(x_flow, Wq, q, NFLOW);
  k_linear64<<<(NMEMB + 3) / 4, 256, 0, stream>>>(x_memb, Wkk, kb, NMEMB);
  k_linear64<<<(NMEMB + 3) / 4, 256, 0, stream>>>(x_memb, Wv, vb, NMEMB);
  k_score<<<EMFN / 4, 256, 0, stream>>>(q, kb, ea_mf, ei_mf, We, score, m);
  k_az<<<EMFN / 4, 256, 0, stream>>>(score, m, ei_mf, vb, z, xc);

  for (long eoff = 0; eoff < PAD_E; eoff += che) {
    long ce = PAD_E - eoff; if (ce > che) ce = che;
    k_h1<<<(int)(ce / 64), 512, 0, stream>>>(ea_ff, (int)eoff, Wk0, bk0, bk1,
                                             Wk1T, h1p, che);
    k_ctr<<<(int)(ce / 256), 512, 0, stream>>>(x_flow, ei_ff, Wk2F, h1p, che,
                                               (int)eoff, aggr, xsum);
  }

  k_final<<<(NFLOW + 3) / 4, 256, 0, stream>>>(x_flow, aggr, xc, z, xsum, bk2,
                                               Wroot, broot, Wo, bo, tau, Wt1, bt1,
                                               Wt2, bt2, out);
}